// Round 16
// baseline (226.439 us; speedup 1.0000x reference)
//
#include <hip/hip_runtime.h>
#include <math.h>

#define SCALEF 0.044194173824159216f   // 1/sqrt(512)

typedef __attribute__((ext_vector_type(8))) short bf16x8;
typedef __attribute__((ext_vector_type(4))) float f32x4;

static __device__ __forceinline__ unsigned short f2bf(float f) {
    union { float f; unsigned int i; } v; v.f = f;
    return (unsigned short)((v.i + 0x7fffu + ((v.i >> 16) & 1u)) >> 16);
}
static __device__ __forceinline__ float bf2f(unsigned short h) {
    union { unsigned int i; float f; } v; v.i = ((unsigned int)h) << 16;
    return v.f;
}
static __device__ __forceinline__ void gload16(const void* g, void* l) {
    __builtin_amdgcn_global_load_lds(
        (const __attribute__((address_space(1))) unsigned int*)g,
        (__attribute__((address_space(3))) unsigned int*)l, 16, 0, 0);
}
// bijective XCD-chunked swizzle (m157/m204): blocks sharing panels land on one XCD.
static __device__ __forceinline__ int swz(int l, int n) {
    return (l & 7) * (n >> 3) + (l >> 3);
}

// ---- rest of prep: Wl/Wt TRANSPOSED bf16, Wvl/Wvt normal, conv pack ----
__global__ __launch_bounds__(256) void prep_rest(
    const float* __restrict__ wl, const float* __restrict__ wt,
    const float4* __restrict__ wvl, const float4* __restrict__ wvt,
    const float* __restrict__ cw,
    ushort4* __restrict__ wlT, ushort4* __restrict__ wtT,
    ushort4* __restrict__ wvlb, ushort4* __restrict__ wvtb,
    unsigned int* __restrict__ wpb)
{
    const long NW = 65536, NCV = 327680;
    for (long i = blockIdx.x * 256L + threadIdx.x; i < 4 * NW + NCV;
         i += gridDim.x * 256L) {
        long r = i;
        if (r < 2 * NW) {                       // transposed weight: wlT or wtT
            const float* src = (r < NW) ? wl : wt;
            ushort4* dst = (r < NW) ? wlT : wtT;
            long u = (r < NW) ? r : r - NW;
            int a = (int)(u >> 7), e4 = (int)(u & 127);
            ushort4 o;
            o.x = f2bf(src[(e4 * 4 + 0) * 512 + a]);
            o.y = f2bf(src[(e4 * 4 + 1) * 512 + a]);
            o.z = f2bf(src[(e4 * 4 + 2) * 512 + a]);
            o.w = f2bf(src[(e4 * 4 + 3) * 512 + a]);
            dst[a * 128 + e4] = o;
            continue;
        }
        r -= 2 * NW;
        const float4* s; ushort4* d;
        if (r < NW) { s = wvl; d = wvlb; }
        else if ((r -= NW) < NW) { s = wvt; d = wvtb; }
        else {
            r -= NW;  // conv unit: wp[e][k*128+c2] = {cw[e][2c2][k], cw[e][2c2+1][k]}
            long e = r / 640, rr = r % 640, k = rr >> 7, c2 = rr & 127;
            unsigned int lo = f2bf(cw[e * 1280 + (2 * c2) * 5 + k]);
            unsigned int hi = f2bf(cw[e * 1280 + (2 * c2 + 1) * 5 + k]);
            wpb[r] = lo | (hi << 16);
            continue;
        }
        float4 f = s[r];
        ushort4 u; u.x = f2bf(f.x); u.y = f2bf(f.y); u.z = f2bf(f.z); u.w = f2bf(f.w);
        d[r] = u;
    }
}

// ------------- in-place row softmax body (bf16), 1/sum folded in -------------
template<int RL>
static __device__ __forceinline__ void sm_body(unsigned short* __restrict__ rowp,
                                               float* __restrict__ redm,
                                               float* __restrict__ reds) {
    constexpr int U = RL / 512;                 // u32 words per thread
    unsigned int* p = (unsigned int*)rowp;
    const int t = threadIdx.x, lane = t & 63, wid = t >> 6;
    unsigned int u[U];
    float v[2 * U];
    #pragma unroll
    for (int i = 0; i < U; ++i) u[i] = p[t + (i << 8)];
    #pragma unroll
    for (int i = 0; i < U; ++i) {
        v[2 * i]     = bf2f((unsigned short)(u[i] & 0xffffu));
        v[2 * i + 1] = bf2f((unsigned short)(u[i] >> 16));
    }
    float m = -INFINITY;
    #pragma unroll
    for (int i = 0; i < 2 * U; ++i) m = fmaxf(m, v[i]);
    #pragma unroll
    for (int k = 1; k < 64; k <<= 1) m = fmaxf(m, __shfl_xor(m, k));
    if (lane == 0) redm[wid] = m;
    __syncthreads();
    m = fmaxf(fmaxf(redm[0], redm[1]), fmaxf(redm[2], redm[3]));
    float s = 0.f, e[2 * U];
    #pragma unroll
    for (int i = 0; i < 2 * U; ++i) { e[i] = __expf(v[i] - m); s += e[i]; }
    #pragma unroll
    for (int k = 1; k < 64; k <<= 1) s += __shfl_xor(s, k);
    if (lane == 0) reds[wid] = s;
    __syncthreads();
    s = reds[0] + reds[1] + reds[2] + reds[3];
    float inv = 1.f / s;
    #pragma unroll
    for (int i = 0; i < U; ++i) {
        unsigned int lo = f2bf(e[2 * i] * inv);
        unsigned int hi = f2bf(e[2 * i + 1] * inv);
        p[t + (i << 8)] = lo | (hi << 16);
    }
}

__global__ __launch_bounds__(256) void softmax_both(unsigned short* __restrict__ S,
                                                    unsigned short* __restrict__ ST) {
    __shared__ float redm[4], reds[4];
    long b = blockIdx.x;
    if (b < 8192) sm_body<2048>(S + b * 2048L, redm, reds);
    else          sm_body<1024>(ST + (b - 8192) * 1024L, redm, reds);
}

// ---------------- MFMA NT GEMM body: C[m,n] = sum_k A[m,k] * B[n,k] ----------
// 128x128 tile, BK=32, 4 waves (2x2 of 64x64), 16x16x32 bf16 MFMA.
// NBUF=3: triple-buffered 48KB, depth-2 prefetch (r9-proven; best for long-K,
//         3 blocks/CU residency).
// NBUF=2: double-buffered 32KB, depth-1 (r12-proven; ~5 blocks/CU residency —
//         used where grid > 768 would otherwise need a second residency round).
// Scalar epilogue (r5-proven). All config compile-time/scalar (r6 lesson).
// AMODE: 0 = row m at A + m*lda.  1 = conv addressing into bf16 tokens.
// EPI:   0 = bf16 out (Cb) * scale
//        1 = +bias(f32, basep) then bf16 out (Cb)
//        2 = f32 base (basep) + acc -> C0 and C1
//        3 = bf16 base (basep) + acc -> C0 and C1
//        4 = bf16 out * scale dual: Cb normal (ldc) AND transposed into
//            (ushort*)C0 with batch stride bsC0, ld bsC1  (score S + S^T)
template<int AMODE, int EPI, int NBUF>
static __device__ __forceinline__ void mm_body(
    char* __restrict__ smc, int bx, int by, int z,
    const unsigned short* __restrict__ A, const unsigned short* __restrict__ B,
    long bsA, long bsB, int lda, int ldb, int K,
    unsigned short* __restrict__ Cb, long bsCb,
    float* __restrict__ C0, long bsC0, float* __restrict__ C1, long bsC1,
    const void* __restrict__ basep, long bsBase, int ldc, float scale)
{
    const int t = threadIdx.x, lane = t & 63, wid = t >> 6;
    const int m0 = by << 7, n0 = bx << 7;
    const unsigned short* Ab = A + (long)z * bsA;
    const unsigned short* Bb = B + (long)z * bsB;

    const int rA0 = wid * 16 + (lane >> 2);
    const int rA1 = rA0 + 64;
    const int cs0 = (lane & 3) ^ ((rA0 >> 1) & 3);
    const int cs1 = (lane & 3) ^ ((rA1 >> 1) & 3);

    long aoff0, aoff1;
    if (AMODE == 0) {
        aoff0 = (long)(m0 + rA0) * lda + cs0 * 8;
        aoff1 = (long)(m0 + rA1) * lda + cs1 * 8;
    } else {
        int ma = m0 + rA0, mb = m0 + rA1;
        aoff0 = (long)(ma >> 11) * 2621440 + (long)(ma & 2047) * 1280 + cs0 * 8;
        aoff1 = (long)(mb >> 11) * 2621440 + (long)(mb & 2047) * 1280 + cs1 * 8;
    }
    const long boff0 = (long)(n0 + rA0) * ldb + cs0 * 8;
    const long boff1 = (long)(n0 + rA1) * ldb + cs1 * 8;

    const int dA0 = (wid << 10), dA1 = ((wid + 4) << 10);
    const int dB0 = 8192 + (wid << 10), dB1 = 8192 + ((wid + 4) << 10);

    const int wr = wid >> 1, wc = wid & 1;
    const int l15 = lane & 15, cslot = lane >> 4;
    int offA[4], offB[4];
    #pragma unroll
    for (int i = 0; i < 4; ++i) {
        int r = wr * 64 + i * 16 + l15;
        offA[i] = r * 64 + ((cslot ^ ((r >> 1) & 3)) << 4);
        int rb = wc * 64 + i * 16 + l15;
        offB[i] = 8192 + rb * 64 + ((cslot ^ ((rb >> 1) & 3)) << 4);
    }

    f32x4 acc[4][4];
    #pragma unroll
    for (int i = 0; i < 4; ++i)
        #pragma unroll
        for (int j = 0; j < 4; ++j)
            acc[i][j] = (f32x4)(0.f);

#define STAGE(p, ktv) do {                                   \
        int kb_ = (ktv);                                     \
        int bo_ = (p) * 16384;                               \
        gload16(Ab + aoff0 + kb_, smc + bo_ + dA0);          \
        gload16(Ab + aoff1 + kb_, smc + bo_ + dA1);          \
        gload16(Bb + boff0 + kb_, smc + bo_ + dB0);          \
        gload16(Bb + boff1 + kb_, smc + bo_ + dB1);          \
    } while (0)
#define COMPUTE(c) do {                                                        \
        const char* base_ = smc + (c) * 16384;                                 \
        bf16x8 af[4], bfr[4];                                                  \
        _Pragma("unroll")                                                      \
        for (int i = 0; i < 4; ++i) af[i]  = *(const bf16x8*)(base_ + offA[i]);\
        _Pragma("unroll")                                                      \
        for (int i = 0; i < 4; ++i) bfr[i] = *(const bf16x8*)(base_ + offB[i]);\
        _Pragma("unroll")                                                      \
        for (int i = 0; i < 4; ++i)                                            \
            _Pragma("unroll")                                                  \
            for (int j = 0; j < 4; ++j)                                        \
                acc[i][j] = __builtin_amdgcn_mfma_f32_16x16x32_bf16(           \
                    af[i], bfr[j], acc[i][j], 0, 0, 0);                        \
    } while (0)

    const int nt = K >> 5;                      // always >= 2 here
    if constexpr (NBUF == 3) {
        STAGE(0, 0);
        STAGE(1, 32);
        int cur = 0;
        for (int it = 0; it < nt; ++it) {
            if (it + 2 < nt) {
                int nx2 = (cur >= 1) ? cur - 1 : 2;   // (cur+2)%3
                STAGE(nx2, (it + 2) << 5);
                asm volatile("s_waitcnt vmcnt(8)" ::: "memory");
            } else if (it + 1 < nt) {
                asm volatile("s_waitcnt vmcnt(4)" ::: "memory");
            } else {
                asm volatile("s_waitcnt vmcnt(0)" ::: "memory");
            }
            __builtin_amdgcn_s_barrier();
            COMPUTE(cur);
            asm volatile("s_waitcnt lgkmcnt(0)" ::: "memory");
            __builtin_amdgcn_s_barrier();
            cur = (cur + 1 == 3) ? 0 : cur + 1;
        }
    } else {
        STAGE(0, 0);
        int cur = 0;
        for (int it = 0; it < nt; ++it) {
            if (it + 1 < nt) {
                STAGE(cur ^ 1, (it + 1) << 5);
                asm volatile("s_waitcnt vmcnt(4)" ::: "memory");
            } else {
                asm volatile("s_waitcnt vmcnt(0)" ::: "memory");
            }
            __builtin_amdgcn_s_barrier();
            COMPUTE(cur);
            asm volatile("s_waitcnt lgkmcnt(0)" ::: "memory");
            __builtin_amdgcn_s_barrier();
            cur ^= 1;
        }
    }
#undef STAGE
#undef COMPUTE

    // epilogue: C/D frag layout col=lane&15, row=(lane>>4)*4+q  [m89-verified]
    const int colb = n0 + wc * 64 + l15;
    const int rowb = m0 + wr * 64 + cslot * 4;
    if (EPI == 4) {
        unsigned short* STp = (unsigned short*)C0;
        #pragma unroll
        for (int i = 0; i < 4; ++i) {
            #pragma unroll
            for (int j = 0; j < 4; ++j) {
                int n = colb + j * 16;
                int mb = rowb + i * 16;
                float v0 = acc[i][j][0] * scale, v1 = acc[i][j][1] * scale;
                float v2 = acc[i][j][2] * scale, v3 = acc[i][j][3] * scale;
                unsigned short b0 = f2bf(v0), b1 = f2bf(v1), b2 = f2bf(v2), b3 = f2bf(v3);
                unsigned short* sp = Cb + (long)z * bsCb + (long)mb * ldc + n;
                sp[0] = b0; sp[ldc] = b1; sp[2 * ldc] = b2; sp[3 * ldc] = b3;
                ushort4 st4; st4.x = b0; st4.y = b1; st4.z = b2; st4.w = b3;
                *(ushort4*)(STp + (long)z * bsC0 + (long)n * bsC1 + mb) = st4;
            }
        }
        return;
    }
    #pragma unroll
    for (int i = 0; i < 4; ++i) {
        #pragma unroll
        for (int j = 0; j < 4; ++j) {
            int n = colb + j * 16;
            #pragma unroll
            for (int q = 0; q < 4; ++q) {
                int m = rowb + i * 16 + q;
                float v = acc[i][j][q];
                if (EPI == 0) {
                    Cb[(long)z * bsCb + (long)m * ldc + n] = f2bf(v * scale);
                } else if (EPI == 1) {
                    v += ((const float*)basep)[n];
                    Cb[(long)m * ldc + n] = f2bf(v);
                } else if (EPI == 2) {
                    float bv = ((const float*)basep)[(long)z * bsBase + (long)m * ldc + n];
                    float o = bv + v;
                    C0[(long)z * bsC0 + (long)m * ldc + n] = o;
                    C1[(long)z * bsC1 + (long)m * ldc + n] = o;
                } else {
                    float bv = bf2f(((const unsigned short*)basep)[(long)z * bsBase + (long)m * ldc + n]);
                    float o = bv + v;
                    C0[(long)z * bsC0 + (long)m * ldc + n] = o;
                    C1[(long)z * bsC1 + (long)m * ldc + n] = o;
                }
            }
        }
    }
}

// ---- cvt (tokens + latents f32->bf16) + Mt GEMM (16 blocks) in one launch ----
// Mt = Wt^T*Wl-fold; wlT/wtT come from the earlier prep_rest launch.
__global__ __launch_bounds__(256) void cvt_mt(
    const float4* __restrict__ tok, const float4* __restrict__ lat,
    ushort4* __restrict__ tokd, ushort4* __restrict__ latd,
    const unsigned short* __restrict__ wtT, const unsigned short* __restrict__ wlT,
    unsigned short* __restrict__ Mt)
{
    __shared__ unsigned short sm[16384];        // 32KB (used by Mt blocks only)
    const int bid = blockIdx.x;
    if (bid < 4096) {
        long t = bid * 256L + threadIdx.x;
        #pragma unroll
        for (int k = 0; k < 5; ++k) {
            long i = t + k * 1048576L;
            float4 f = tok[i];
            ushort4 u; u.x = f2bf(f.x); u.y = f2bf(f.y); u.z = f2bf(f.z); u.w = f2bf(f.w);
            tokd[i] = u;
        }
        float4 f = lat[t];
        ushort4 u; u.x = f2bf(f.x); u.y = f2bf(f.y); u.z = f2bf(f.z); u.w = f2bf(f.w);
        latd[t] = u;
    } else {                                    // Mt: grid 4x4, 16 blocks
        int l = bid - 4096;
        mm_body<0, 0, 2>((char*)sm, l & 3, l >> 2, 0, wtT, wlT, 0, 0, 512, 512, 512,
                         Mt, 0, nullptr, 0, nullptr, 0, nullptr, 0, 512, 1.f);
    }
}

// ---- grouped phase 1: conv (512) + V_latT (256) = exactly 768 blocks ----
// job-contiguous (r9-proven; r10/r11 interleaves broke L2 locality).
__global__ __launch_bounds__(256) void gemm_g1(
    const unsigned short* __restrict__ tknb, const unsigned short* __restrict__ wpb,
    const float* __restrict__ conv_b, unsigned short* __restrict__ tokb,
    const unsigned short* __restrict__ latb,
    const unsigned short* __restrict__ wvlb, unsigned short* __restrict__ vlT)
{
    __shared__ unsigned short sm[24576];
    char* smc = (char*)sm;
    const int bid = blockIdx.x;
    if (bid < 512) {                            // conv: grid 4x128, K=1280 (longest first)
        int l = swz(bid, 512);
        mm_body<1, 1, 3>(smc, l & 3, l >> 2, 0, tknb, wpb, 0, 0, 1280, 1280, 1280,
                         tokb, 0, nullptr, 0, nullptr, 0, conv_b, 0, 512, 1.f);
    } else {                                    // V_latT: grid 8x4x8
        int l = swz(bid - 512, 256);
        mm_body<0, 0, 3>(smc, l & 7, (l >> 3) & 3, l >> 5, wvlb, latb, 0, 524288,
                         512, 512, 512, vlT, 524288, nullptr, 0, nullptr, 0,
                         nullptr, 0, 1024, 1.f);
    }
}

// ---- grouped phase 2: V_tokT (512) + P = lat*M (256) ----
__global__ __launch_bounds__(256) void gemm_g2(
    const unsigned short* __restrict__ tokb,
    const unsigned short* __restrict__ wvtb, unsigned short* __restrict__ vtT,
    const unsigned short* __restrict__ latb, const unsigned short* __restrict__ Mt,
    unsigned short* __restrict__ P)
{
    __shared__ unsigned short sm[24576];
    char* smc = (char*)sm;
    const int bid = blockIdx.x;
    if (bid < 512) {                            // V_tokT: grid 16x4x8
        int l = swz(bid, 512);
        mm_body<0, 0, 3>(smc, l & 15, (l >> 4) & 3, l >> 6, wvtb, tokb, 0, 1048576,
                         512, 512, 512, vtT, 1048576, nullptr, 0, nullptr, 0,
                         nullptr, 0, 2048, 1.f);
    } else {                                    // P: grid 4x64 (B = Mt, 0.5MB, L2-resident)
        int l = swz(bid - 512, 256);
        mm_body<0, 0, 3>(smc, l & 3, l >> 2, 0, latb, Mt, 0, 0, 512, 512, 512,
                         P, 0, nullptr, 0, nullptr, 0, nullptr, 0, 512, 1.f);
    }
}

// ---- score GEMM: S = scale * P tok^T, dual-written as S and S^T ----
// NBUF=2 (32KB LDS): 1024 blocks fully co-resident (48KB would force a
// 768+256 two-round schedule = +33% duration; r12 data showed the non-g3
// kernels preferred full residency).
__global__ __launch_bounds__(256) void gemm_sc(
    const unsigned short* __restrict__ P, const unsigned short* __restrict__ tokb,
    unsigned short* __restrict__ S, unsigned short* __restrict__ ST)
{
    __shared__ unsigned short sm[16384];
    int l = swz((int)blockIdx.x, 1024);         // grid 16x8x8: one z per XCD chunk
    mm_body<0, 4, 2>((char*)sm, l & 15, (l >> 4) & 7, l >> 7,
                     P, tokb, 524288, 1048576, 512, 512, 512,
                     S, 2097152, (float*)ST, 2097152, nullptr, 1024,
                     nullptr, 0, 2048, SCALEF);
}

// ---- grouped phase 3: both delta GEMMs, fused residual + dual write ----
__global__ __launch_bounds__(256) void gemm_g3(
    const unsigned short* __restrict__ S, const unsigned short* __restrict__ ST,
    const unsigned short* __restrict__ vlT, const unsigned short* __restrict__ vtT,
    const float* __restrict__ latents, const unsigned short* __restrict__ tokb,
    float* __restrict__ out)
{
    __shared__ unsigned short sm[24576];
    char* smc = (char*)sm;
    const int bid = blockIdx.x;
    if (bid < 256) {                            // delta_lat: grid 4x8x8, K=2048 (longest first)
        int l = swz(bid, 256);
        mm_body<0, 2, 3>(smc, l & 3, (l >> 2) & 7, l >> 5, S, vtT, 2097152, 1048576,
                         2048, 2048, 2048, nullptr, 0,
                         out, 524288, out + 12582912, 1572864,
                         latents, 524288, 512, 1.f);
    } else {                                    // delta_tok: grid 4x16x8, K=1024
        int l = swz(bid - 256, 512);
        mm_body<0, 3, 3>(smc, l & 3, (l >> 2) & 15, l >> 6, ST, vlT, 2097152, 524288,
                         1024, 1024, 1024, nullptr, 0,
                         out + 4194304, 1048576, out + 12582912 + 524288, 1572864,
                         tokb, 1048576, 512, 1.f);
    }
}

extern "C" void kernel_launch(void* const* d_in, const int* in_sizes, int n_in,
                              void* d_out, int out_size, void* d_ws, size_t ws_size,
                              hipStream_t stream)
{
    const float* latents = (const float*)d_in[0];
    const float* tokens  = (const float*)d_in[1];
    const float* W_lat   = (const float*)d_in[2];
    const float* W_tok   = (const float*)d_in[3];
    const float* W_vlat  = (const float*)d_in[4];
    const float* W_vtok  = (const float*)d_in[5];
    const float* conv_w  = (const float*)d_in[6];
    const float* conv_b  = (const float*)d_in[7];
    float* out = (float*)d_out;
    char* ws = (char*)d_ws;

    // workspace layout (bytes)
    unsigned short* S    = (unsigned short*)(ws);              // 8x1024x2048 bf16 = 33,554,432
    unsigned short* ST   = (unsigned short*)(ws + 33554432);   // 8x2048x1024 bf16
    unsigned short* tokb = (unsigned short*)(ws + 67108864);   // 8x2048x512  bf16 = 16,777,216
    unsigned short* latb = (unsigned short*)(ws + 83886080);   // 8x1024x512  bf16 =  8,388,608
    unsigned short* P    = (unsigned short*)(ws + 92274688);   // 8x1024x512  bf16 =  8,388,608
    unsigned short* Mt   = (unsigned short*)(ws + 100663296);  // 512x512     bf16 =    524,288
    unsigned short* vlT  = (unsigned short*)(ws + 117440512);  // 8x512x1024 =  8,388,608
    unsigned short* vtT  = (unsigned short*)(ws + 125829120);  // 8x512x2048 = 16,777,216
    unsigned short* wpb  = (unsigned short*)(ws + 142606336);  // 512x1280   =  1,310,720
    unsigned short* wlT  = (unsigned short*)(ws + 143917056);  // 512x512 x4 =  2,097,152
    unsigned short* wtT  = (unsigned short*)(ws + 144441344);
    unsigned short* wvlb = (unsigned short*)(ws + 144965632);
    unsigned short* wvtb = (unsigned short*)(ws + 145489920);  // end 146,014,208
    // tokens-as-bf16 scratch lives in the concat region of d_out (overwritten by g3)
    unsigned short* tknb = (unsigned short*)(out + 12582912);  // 41,943,040 B <= 50,331,648 B

    // 1) weight prep FIRST (produces wlT/wtT for the Mt blocks in cvt_mt)
    prep_rest<<<512, 256, 0, stream>>>(
        W_lat, W_tok, (const float4*)W_vlat, (const float4*)W_vtok, conv_w,
        (ushort4*)wlT, (ushort4*)wtT, (ushort4*)wvlb, (ushort4*)wvtb,
        (unsigned int*)wpb);

    // 2) tokens/latents conversion + Mt GEMM (one launch, 4112 blocks)
    cvt_mt<<<4112, 256, 0, stream>>>((const float4*)tokens, (const float4*)latents,
                                     (ushort4*)tknb, (ushort4*)latb, wtT, wlT, Mt);

    // 3) conv-GEMM + V_latT (one launch, exactly 768 blocks)
    gemm_g1<<<768, 256, 0, stream>>>(tknb, wpb, conv_b, tokb, latb, wvlb, vlT);

    // 4) V_tokT + P = lat*M (one launch, 768 blocks)
    gemm_g2<<<768, 256, 0, stream>>>(tokb, wvtb, vtT, latb, Mt, P);

    // 5) score matrix S = scale * P tok^T, dual-written as S and S^T (full residency)
    gemm_sc<<<1024, 256, 0, stream>>>(P, tokb, S, ST);

    // 6) softmax in place, both matrices, one launch
    softmax_both<<<24576, 256, 0, stream>>>(S, ST);

    // 7) both delta GEMMs (one launch, 768 blocks)
    gemm_g3<<<768, 256, 0, stream>>>(S, ST, vlT, vtT, latents, tokb, out);
}

// Round 17
// 205.843 us; speedup vs baseline: 1.1001x; 1.1001x over previous
//
#include <hip/hip_runtime.h>
#include <math.h>

#define SCALEF 0.044194173824159216f   // 1/sqrt(512)

typedef __attribute__((ext_vector_type(8))) short bf16x8;
typedef __attribute__((ext_vector_type(4))) float f32x4;

static __device__ __forceinline__ unsigned short f2bf(float f) {
    union { float f; unsigned int i; } v; v.f = f;
    return (unsigned short)((v.i + 0x7fffu + ((v.i >> 16) & 1u)) >> 16);
}
static __device__ __forceinline__ float bf2f(unsigned short h) {
    union { unsigned int i; float f; } v; v.i = ((unsigned int)h) << 16;
    return v.f;
}
static __device__ __forceinline__ void gload16(const void* g, void* l) {
    __builtin_amdgcn_global_load_lds(
        (const __attribute__((address_space(1))) unsigned int*)g,
        (__attribute__((address_space(3))) unsigned int*)l, 16, 0, 0);
}
// bijective XCD-chunked swizzle (m157/m204): blocks sharing panels land on one XCD.
static __device__ __forceinline__ int swz(int l, int n) {
    return (l & 7) * (n >> 3) + (l >> 3);
}

// ---- rest of prep: Wl/Wt TRANSPOSED bf16, Wvl/Wvt normal, conv pack ----
__global__ __launch_bounds__(256) void prep_rest(
    const float* __restrict__ wl, const float* __restrict__ wt,
    const float4* __restrict__ wvl, const float4* __restrict__ wvt,
    const float* __restrict__ cw,
    ushort4* __restrict__ wlT, ushort4* __restrict__ wtT,
    ushort4* __restrict__ wvlb, ushort4* __restrict__ wvtb,
    unsigned int* __restrict__ wpb)
{
    const long NW = 65536, NCV = 327680;
    for (long i = blockIdx.x * 256L + threadIdx.x; i < 4 * NW + NCV;
         i += gridDim.x * 256L) {
        long r = i;
        if (r < 2 * NW) {                       // transposed weight: wlT or wtT
            const float* src = (r < NW) ? wl : wt;
            ushort4* dst = (r < NW) ? wlT : wtT;
            long u = (r < NW) ? r : r - NW;
            int a = (int)(u >> 7), e4 = (int)(u & 127);
            ushort4 o;
            o.x = f2bf(src[(e4 * 4 + 0) * 512 + a]);
            o.y = f2bf(src[(e4 * 4 + 1) * 512 + a]);
            o.z = f2bf(src[(e4 * 4 + 2) * 512 + a]);
            o.w = f2bf(src[(e4 * 4 + 3) * 512 + a]);
            dst[a * 128 + e4] = o;
            continue;
        }
        r -= 2 * NW;
        const float4* s; ushort4* d;
        if (r < NW) { s = wvl; d = wvlb; }
        else if ((r -= NW) < NW) { s = wvt; d = wvtb; }
        else {
            r -= NW;  // conv unit: wp[e][k*128+c2] = {cw[e][2c2][k], cw[e][2c2+1][k]}
            long e = r / 640, rr = r % 640, k = rr >> 7, c2 = rr & 127;
            unsigned int lo = f2bf(cw[e * 1280 + (2 * c2) * 5 + k]);
            unsigned int hi = f2bf(cw[e * 1280 + (2 * c2 + 1) * 5 + k]);
            wpb[r] = lo | (hi << 16);
            continue;
        }
        float4 f = s[r];
        ushort4 u; u.x = f2bf(f.x); u.y = f2bf(f.y); u.z = f2bf(f.z); u.w = f2bf(f.w);
        d[r] = u;
    }
}

// ---------------- MFMA NT GEMM body: C[m,n] = sum_k A[m,k] * B[n,k] ----------
// 128x128 tile, BK=32, 4 waves (2x2 of 64x64), 16x16x32 bf16 MFMA.
// NBUF=3: triple-buffered 48KB, depth-2 prefetch (r9-proven).
// NBUF=2: double-buffered 32KB, depth-1 (r12-proven; full residency at 1024 blk).
// Scalar epilogue (r5-proven). All config compile-time/scalar (r6 lesson).
// AMODE: 0 = row m at A + m*lda.  1 = conv addressing into bf16 tokens.
// EPI:   0 = bf16 out (Cb) * scale
//        1 = +bias(f32, basep) then bf16 out (Cb)
//        2 = f32 base + acc -> C0,C1    3 = bf16 base + acc -> C0,C1
//        4 = EXP-score dual write: e=exp(v*scale); Cb normal (ldc) AND transposed
//            into (ushort*)C0 (ld bsC1); deterministic partial sums:
//            row-partials -> sumP0[z][m][32] (p=bx*2+wc),
//            col-partials -> sumP1[z][n][16] (p=by*2+wr).   (softmax fused out)
//        5 = f32 base + acc*inv -> C0,C1  (inv = 1/sum of 32 partials, rows 1024)
//        6 = bf16 base + acc*inv -> C0,C1 (inv = 1/sum of 16 partials, rows 2048)
template<int AMODE, int EPI, int NBUF, int NP = 0>
static __device__ __forceinline__ void mm_body(
    char* __restrict__ smc, int bx, int by, int z,
    const unsigned short* __restrict__ A, const unsigned short* __restrict__ B,
    long bsA, long bsB, int lda, int ldb, int K,
    unsigned short* __restrict__ Cb, long bsCb,
    float* __restrict__ C0, long bsC0, float* __restrict__ C1, long bsC1,
    const void* __restrict__ basep, long bsBase, int ldc, float scale,
    float* __restrict__ sumP0, float* __restrict__ sumP1)
{
    const int t = threadIdx.x, lane = t & 63, wid = t >> 6;
    const int m0 = by << 7, n0 = bx << 7;
    const unsigned short* Ab = A + (long)z * bsA;
    const unsigned short* Bb = B + (long)z * bsB;

    const int rA0 = wid * 16 + (lane >> 2);
    const int rA1 = rA0 + 64;
    const int cs0 = (lane & 3) ^ ((rA0 >> 1) & 3);
    const int cs1 = (lane & 3) ^ ((rA1 >> 1) & 3);

    long aoff0, aoff1;
    if (AMODE == 0) {
        aoff0 = (long)(m0 + rA0) * lda + cs0 * 8;
        aoff1 = (long)(m0 + rA1) * lda + cs1 * 8;
    } else {
        int ma = m0 + rA0, mb = m0 + rA1;
        aoff0 = (long)(ma >> 11) * 2621440 + (long)(ma & 2047) * 1280 + cs0 * 8;
        aoff1 = (long)(mb >> 11) * 2621440 + (long)(mb & 2047) * 1280 + cs1 * 8;
    }
    const long boff0 = (long)(n0 + rA0) * ldb + cs0 * 8;
    const long boff1 = (long)(n0 + rA1) * ldb + cs1 * 8;

    const int dA0 = (wid << 10), dA1 = ((wid + 4) << 10);
    const int dB0 = 8192 + (wid << 10), dB1 = 8192 + ((wid + 4) << 10);

    const int wr = wid >> 1, wc = wid & 1;
    const int l15 = lane & 15, cslot = lane >> 4;
    int offA[4], offB[4];
    #pragma unroll
    for (int i = 0; i < 4; ++i) {
        int r = wr * 64 + i * 16 + l15;
        offA[i] = r * 64 + ((cslot ^ ((r >> 1) & 3)) << 4);
        int rb = wc * 64 + i * 16 + l15;
        offB[i] = 8192 + rb * 64 + ((cslot ^ ((rb >> 1) & 3)) << 4);
    }

    f32x4 acc[4][4];
    #pragma unroll
    for (int i = 0; i < 4; ++i)
        #pragma unroll
        for (int j = 0; j < 4; ++j)
            acc[i][j] = (f32x4)(0.f);

#define STAGE(p, ktv) do {                                   \
        int kb_ = (ktv);                                     \
        int bo_ = (p) * 16384;                               \
        gload16(Ab + aoff0 + kb_, smc + bo_ + dA0);          \
        gload16(Ab + aoff1 + kb_, smc + bo_ + dA1);          \
        gload16(Bb + boff0 + kb_, smc + bo_ + dB0);          \
        gload16(Bb + boff1 + kb_, smc + bo_ + dB1);          \
    } while (0)
#define COMPUTE(c) do {                                                        \
        const char* base_ = smc + (c) * 16384;                                 \
        bf16x8 af[4], bfr[4];                                                  \
        _Pragma("unroll")                                                      \
        for (int i = 0; i < 4; ++i) af[i]  = *(const bf16x8*)(base_ + offA[i]);\
        _Pragma("unroll")                                                      \
        for (int i = 0; i < 4; ++i) bfr[i] = *(const bf16x8*)(base_ + offB[i]);\
        _Pragma("unroll")                                                      \
        for (int i = 0; i < 4; ++i)                                            \
            _Pragma("unroll")                                                  \
            for (int j = 0; j < 4; ++j)                                        \
                acc[i][j] = __builtin_amdgcn_mfma_f32_16x16x32_bf16(           \
                    af[i], bfr[j], acc[i][j], 0, 0, 0);                        \
    } while (0)

    const int nt = K >> 5;                      // always >= 2 here
    if constexpr (NBUF == 3) {
        STAGE(0, 0);
        STAGE(1, 32);
        int cur = 0;
        for (int it = 0; it < nt; ++it) {
            if (it + 2 < nt) {
                int nx2 = (cur >= 1) ? cur - 1 : 2;   // (cur+2)%3
                STAGE(nx2, (it + 2) << 5);
                asm volatile("s_waitcnt vmcnt(8)" ::: "memory");
            } else if (it + 1 < nt) {
                asm volatile("s_waitcnt vmcnt(4)" ::: "memory");
            } else {
                asm volatile("s_waitcnt vmcnt(0)" ::: "memory");
            }
            __builtin_amdgcn_s_barrier();
            COMPUTE(cur);
            asm volatile("s_waitcnt lgkmcnt(0)" ::: "memory");
            __builtin_amdgcn_s_barrier();
            cur = (cur + 1 == 3) ? 0 : cur + 1;
        }
    } else {
        STAGE(0, 0);
        int cur = 0;
        for (int it = 0; it < nt; ++it) {
            if (it + 1 < nt) {
                STAGE(cur ^ 1, (it + 1) << 5);
                asm volatile("s_waitcnt vmcnt(4)" ::: "memory");
            } else {
                asm volatile("s_waitcnt vmcnt(0)" ::: "memory");
            }
            __builtin_amdgcn_s_barrier();
            COMPUTE(cur);
            asm volatile("s_waitcnt lgkmcnt(0)" ::: "memory");
            __builtin_amdgcn_s_barrier();
            cur ^= 1;
        }
    }
#undef STAGE
#undef COMPUTE

    // epilogue: C/D frag layout col=lane&15, row=(lane>>4)*4+q  [m89-verified]
    const int colb = n0 + wc * 64 + l15;
    const int rowb = m0 + wr * 64 + cslot * 4;

    if (EPI == 4) {
        unsigned short* STp = (unsigned short*)C0;
        // exp(scale*v) in place
        #pragma unroll
        for (int i = 0; i < 4; ++i)
            #pragma unroll
            for (int j = 0; j < 4; ++j)
                #pragma unroll
                for (int q = 0; q < 4; ++q)
                    acc[i][j][q] = __expf(acc[i][j][q] * scale);
        // dual write (expS normal + transposed)
        #pragma unroll
        for (int i = 0; i < 4; ++i) {
            #pragma unroll
            for (int j = 0; j < 4; ++j) {
                int n = colb + j * 16;
                int mb = rowb + i * 16;
                unsigned short b0 = f2bf(acc[i][j][0]), b1 = f2bf(acc[i][j][1]);
                unsigned short b2 = f2bf(acc[i][j][2]), b3 = f2bf(acc[i][j][3]);
                unsigned short* sp = Cb + (long)z * bsCb + (long)mb * ldc + n;
                sp[0] = b0; sp[ldc] = b1; sp[2 * ldc] = b2; sp[3 * ldc] = b3;
                ushort4 st4; st4.x = b0; st4.y = b1; st4.z = b2; st4.w = b3;
                *(ushort4*)(STp + (long)z * bsC0 + (long)n * bsC1 + mb) = st4;
            }
        }
        // deterministic row partial sums (this wave's 64-col span)
        #pragma unroll
        for (int i = 0; i < 4; ++i) {
            #pragma unroll
            for (int q = 0; q < 4; ++q) {
                float rs = acc[i][0][q] + acc[i][1][q] + acc[i][2][q] + acc[i][3][q];
                #pragma unroll
                for (int msk = 1; msk < 16; msk <<= 1) rs += __shfl_xor(rs, msk);
                if (l15 == 0) {
                    int m = rowb + i * 16 + q;
                    sumP0[((long)z * 1024 + m) * 32 + bx * 2 + wc] = rs;
                }
            }
        }
        // deterministic col partial sums (this wave's 64-row span)
        #pragma unroll
        for (int j = 0; j < 4; ++j) {
            float cs = 0.f;
            #pragma unroll
            for (int i = 0; i < 4; ++i)
                #pragma unroll
                for (int q = 0; q < 4; ++q) cs += acc[i][j][q];
            cs += __shfl_xor(cs, 16);
            cs += __shfl_xor(cs, 32);
            if (cslot == 0) {
                int n = colb + j * 16;
                sumP1[((long)z * 2048 + n) * 16 + by * 2 + wr] = cs;
            }
        }
        return;
    }

    float* invt = nullptr;
    if (EPI == 5 || EPI == 6) {
        invt = (float*)smc;                     // LDS free after main loop
        if (t < 128) {
            const int rows = (EPI == 5) ? 1024 : 2048;
            const float* pp = sumP0 + ((long)z * rows + m0 + t) * NP;
            float s = 0.f;
            #pragma unroll
            for (int k = 0; k < NP; ++k) s += pp[k];
            invt[t] = 1.f / s;
        }
        __syncthreads();
    }

    #pragma unroll
    for (int i = 0; i < 4; ++i) {
        #pragma unroll
        for (int j = 0; j < 4; ++j) {
            int n = colb + j * 16;
            #pragma unroll
            for (int q = 0; q < 4; ++q) {
                int m = rowb + i * 16 + q;
                float v = acc[i][j][q];
                if (EPI == 0) {
                    Cb[(long)z * bsCb + (long)m * ldc + n] = f2bf(v * scale);
                } else if (EPI == 1) {
                    v += ((const float*)basep)[n];
                    Cb[(long)m * ldc + n] = f2bf(v);
                } else if (EPI == 2) {
                    float bv = ((const float*)basep)[(long)z * bsBase + (long)m * ldc + n];
                    float o = bv + v;
                    C0[(long)z * bsC0 + (long)m * ldc + n] = o;
                    C1[(long)z * bsC1 + (long)m * ldc + n] = o;
                } else if (EPI == 3) {
                    float bv = bf2f(((const unsigned short*)basep)[(long)z * bsBase + (long)m * ldc + n]);
                    float o = bv + v;
                    C0[(long)z * bsC0 + (long)m * ldc + n] = o;
                    C1[(long)z * bsC1 + (long)m * ldc + n] = o;
                } else if (EPI == 5) {
                    float vv = v * invt[(rowb - m0) + i * 16 + q];
                    float bv = ((const float*)basep)[(long)z * bsBase + (long)m * ldc + n];
                    float o = bv + vv;
                    C0[(long)z * bsC0 + (long)m * ldc + n] = o;
                    C1[(long)z * bsC1 + (long)m * ldc + n] = o;
                } else if (EPI == 6) {
                    float vv = v * invt[(rowb - m0) + i * 16 + q];
                    float bv = bf2f(((const unsigned short*)basep)[(long)z * bsBase + (long)m * ldc + n]);
                    float o = bv + vv;
                    C0[(long)z * bsC0 + (long)m * ldc + n] = o;
                    C1[(long)z * bsC1 + (long)m * ldc + n] = o;
                }
            }
        }
    }
}

// ---- cvt (tokens + latents f32->bf16) + Mt GEMM (16 blocks) in one launch ----
__global__ __launch_bounds__(256) void cvt_mt(
    const float4* __restrict__ tok, const float4* __restrict__ lat,
    ushort4* __restrict__ tokd, ushort4* __restrict__ latd,
    const unsigned short* __restrict__ wtT, const unsigned short* __restrict__ wlT,
    unsigned short* __restrict__ Mt)
{
    __shared__ unsigned short sm[16384];        // 32KB (used by Mt blocks only)
    const int bid = blockIdx.x;
    if (bid < 4096) {
        long t = bid * 256L + threadIdx.x;
        #pragma unroll
        for (int k = 0; k < 5; ++k) {
            long i = t + k * 1048576L;
            float4 f = tok[i];
            ushort4 u; u.x = f2bf(f.x); u.y = f2bf(f.y); u.z = f2bf(f.z); u.w = f2bf(f.w);
            tokd[i] = u;
        }
        float4 f = lat[t];
        ushort4 u; u.x = f2bf(f.x); u.y = f2bf(f.y); u.z = f2bf(f.z); u.w = f2bf(f.w);
        latd[t] = u;
    } else {                                    // Mt: grid 4x4, 16 blocks
        int l = bid - 4096;
        mm_body<0, 0, 2>((char*)sm, l & 3, l >> 2, 0, wtT, wlT, 0, 0, 512, 512, 512,
                         Mt, 0, nullptr, 0, nullptr, 0, nullptr, 0, 512, 1.f,
                         nullptr, nullptr);
    }
}

// ---- grouped phase 1: conv (512) + V_latT (256) = exactly 768 blocks ----
__global__ __launch_bounds__(256) void gemm_g1(
    const unsigned short* __restrict__ tknb, const unsigned short* __restrict__ wpb,
    const float* __restrict__ conv_b, unsigned short* __restrict__ tokb,
    const unsigned short* __restrict__ latb,
    const unsigned short* __restrict__ wvlb, unsigned short* __restrict__ vlT)
{
    __shared__ unsigned short sm[24576];
    char* smc = (char*)sm;
    const int bid = blockIdx.x;
    if (bid < 512) {                            // conv: grid 4x128, K=1280 (longest first)
        int l = swz(bid, 512);
        mm_body<1, 1, 3>(smc, l & 3, l >> 2, 0, tknb, wpb, 0, 0, 1280, 1280, 1280,
                         tokb, 0, nullptr, 0, nullptr, 0, conv_b, 0, 512, 1.f,
                         nullptr, nullptr);
    } else {                                    // V_latT: grid 8x4x8
        int l = swz(bid - 512, 256);
        mm_body<0, 0, 3>(smc, l & 7, (l >> 3) & 3, l >> 5, wvlb, latb, 0, 524288,
                         512, 512, 512, vlT, 524288, nullptr, 0, nullptr, 0,
                         nullptr, 0, 1024, 1.f, nullptr, nullptr);
    }
}

// ---- grouped phase 2: V_tokT (512) + P = lat*M (256) ----
__global__ __launch_bounds__(256) void gemm_g2(
    const unsigned short* __restrict__ tokb,
    const unsigned short* __restrict__ wvtb, unsigned short* __restrict__ vtT,
    const unsigned short* __restrict__ latb, const unsigned short* __restrict__ Mt,
    unsigned short* __restrict__ P)
{
    __shared__ unsigned short sm[24576];
    char* smc = (char*)sm;
    const int bid = blockIdx.x;
    if (bid < 512) {                            // V_tokT: grid 16x4x8
        int l = swz(bid, 512);
        mm_body<0, 0, 3>(smc, l & 15, (l >> 4) & 3, l >> 6, wvtb, tokb, 0, 1048576,
                         512, 512, 512, vtT, 1048576, nullptr, 0, nullptr, 0,
                         nullptr, 0, 2048, 1.f, nullptr, nullptr);
    } else {                                    // P: grid 4x64 (B = Mt, L2-resident)
        int l = swz(bid - 512, 256);
        mm_body<0, 0, 3>(smc, l & 3, l >> 2, 0, latb, Mt, 0, 0, 512, 512, 512,
                         P, 0, nullptr, 0, nullptr, 0, nullptr, 0, 512, 1.f,
                         nullptr, nullptr);
    }
}

// ---- score GEMM: expS = exp(scale * P tok^T), dual-written + partial sums ----
__global__ __launch_bounds__(256) void gemm_sc(
    const unsigned short* __restrict__ P, const unsigned short* __restrict__ tokb,
    unsigned short* __restrict__ S, unsigned short* __restrict__ ST,
    float* __restrict__ rsumP, float* __restrict__ csumP)
{
    __shared__ unsigned short sm[16384];
    int l = swz((int)blockIdx.x, 1024);         // grid 16x8x8: one z per XCD chunk
    mm_body<0, 4, 2>((char*)sm, l & 15, (l >> 4) & 7, l >> 7,
                     P, tokb, 524288, 1048576, 512, 512, 512,
                     S, 2097152, (float*)ST, 2097152, nullptr, 1024,
                     nullptr, 0, 2048, SCALEF, rsumP, csumP);
}

// ---- grouped phase 3: delta GEMMs with fused 1/rowsum + residual + dual write
__global__ __launch_bounds__(256) void gemm_g3(
    const unsigned short* __restrict__ S, const unsigned short* __restrict__ ST,
    const unsigned short* __restrict__ vlT, const unsigned short* __restrict__ vtT,
    const float* __restrict__ latents, const unsigned short* __restrict__ tokb,
    const float* __restrict__ rsumP, const float* __restrict__ csumP,
    float* __restrict__ out)
{
    __shared__ unsigned short sm[24576];
    char* smc = (char*)sm;
    const int bid = blockIdx.x;
    if (bid < 256) {                            // delta_lat: grid 4x8x8, K=2048
        int l = swz(bid, 256);
        mm_body<0, 5, 3, 32>(smc, l & 3, (l >> 2) & 7, l >> 5, S, vtT, 2097152, 1048576,
                             2048, 2048, 2048, nullptr, 0,
                             out, 524288, out + 12582912, 1572864,
                             latents, 524288, 512, 1.f, (float*)rsumP, nullptr);
    } else {                                    // delta_tok: grid 4x16x8, K=1024
        int l = swz(bid - 256, 512);
        mm_body<0, 6, 3, 16>(smc, l & 3, (l >> 2) & 15, l >> 6, ST, vlT, 2097152, 524288,
                             1024, 1024, 1024, nullptr, 0,
                             out + 4194304, 1048576, out + 12582912 + 524288, 1572864,
                             tokb, 1048576, 512, 1.f, (float*)csumP, nullptr);
    }
}

extern "C" void kernel_launch(void* const* d_in, const int* in_sizes, int n_in,
                              void* d_out, int out_size, void* d_ws, size_t ws_size,
                              hipStream_t stream)
{
    const float* latents = (const float*)d_in[0];
    const float* tokens  = (const float*)d_in[1];
    const float* W_lat   = (const float*)d_in[2];
    const float* W_tok   = (const float*)d_in[3];
    const float* W_vlat  = (const float*)d_in[4];
    const float* W_vtok  = (const float*)d_in[5];
    const float* conv_w  = (const float*)d_in[6];
    const float* conv_b  = (const float*)d_in[7];
    float* out = (float*)d_out;
    char* ws = (char*)d_ws;

    // workspace layout (bytes)
    unsigned short* S    = (unsigned short*)(ws);              // 8x1024x2048 bf16 = 33,554,432
    unsigned short* ST   = (unsigned short*)(ws + 33554432);   // 8x2048x1024 bf16
    unsigned short* tokb = (unsigned short*)(ws + 67108864);   // 8x2048x512  bf16 = 16,777,216
    unsigned short* latb = (unsigned short*)(ws + 83886080);   // 8x1024x512  bf16 =  8,388,608
    unsigned short* P    = (unsigned short*)(ws + 92274688);   // 8x1024x512  bf16 =  8,388,608
    unsigned short* Mt   = (unsigned short*)(ws + 100663296);  // 512x512     bf16 =    524,288
    float*          rsumP= (float*)(ws + 101187584);           // 8x1024x32 f32 = 1,048,576
    float*          csumP= (float*)(ws + 102236160);           // 8x2048x16 f32 = 1,048,576
    unsigned short* vlT  = (unsigned short*)(ws + 117440512);  // 8x512x1024 =  8,388,608
    unsigned short* vtT  = (unsigned short*)(ws + 125829120);  // 8x512x2048 = 16,777,216
    unsigned short* wpb  = (unsigned short*)(ws + 142606336);  // 512x1280   =  1,310,720
    unsigned short* wlT  = (unsigned short*)(ws + 143917056);  // 512x512 x4 =  2,097,152
    unsigned short* wtT  = (unsigned short*)(ws + 144441344);
    unsigned short* wvlb = (unsigned short*)(ws + 144965632);
    unsigned short* wvtb = (unsigned short*)(ws + 145489920);  // end 146,014,208
    // tokens-as-bf16 scratch lives in the concat region of d_out (overwritten by g3)
    unsigned short* tknb = (unsigned short*)(out + 12582912);  // 41,943,040 B <= 50,331,648 B

    // 1) weight prep FIRST (produces wlT/wtT for the Mt blocks in cvt_mt)
    prep_rest<<<512, 256, 0, stream>>>(
        W_lat, W_tok, (const float4*)W_vlat, (const float4*)W_vtok, conv_w,
        (ushort4*)wlT, (ushort4*)wtT, (ushort4*)wvlb, (ushort4*)wvtb,
        (unsigned int*)wpb);

    // 2) tokens/latents conversion + Mt GEMM (one launch, 4112 blocks)
    cvt_mt<<<4112, 256, 0, stream>>>((const float4*)tokens, (const float4*)latents,
                                     (ushort4*)tknb, (ushort4*)latb, wtT, wlT, Mt);

    // 3) conv-GEMM + V_latT (one launch, exactly 768 blocks)
    gemm_g1<<<768, 256, 0, stream>>>(tknb, wpb, conv_b, tokb, latb, wvlb, vlT);

    // 4) V_tokT + P = lat*M (one launch, 768 blocks)
    gemm_g2<<<768, 256, 0, stream>>>(tokb, wvtb, vtT, latb, Mt, P);

    // 5) expS = exp(scale * P tok^T) dual-written + deterministic partial sums
    //    (softmax pass eliminated: normalization folded into g3's epilogue)
    gemm_sc<<<1024, 256, 0, stream>>>(P, tokb, S, ST, rsumP, csumP);

    // 6) both delta GEMMs with fused 1/rowsum (one launch, 768 blocks)
    gemm_g3<<<768, 256, 0, stream>>>(S, ST, vlT, vtT, latents, tokb,
                                     rsumP, csumP, out);
}

// Round 18
// 202.161 us; speedup vs baseline: 1.1201x; 1.0182x over previous
//
#include <hip/hip_runtime.h>
#include <math.h>

#define SCALEF 0.044194173824159216f   // 1/sqrt(512)

typedef __attribute__((ext_vector_type(8))) short bf16x8;
typedef __attribute__((ext_vector_type(4))) float f32x4;

static __device__ __forceinline__ unsigned short f2bf(float f) {
    union { float f; unsigned int i; } v; v.f = f;
    return (unsigned short)((v.i + 0x7fffu + ((v.i >> 16) & 1u)) >> 16);
}
static __device__ __forceinline__ float bf2f(unsigned short h) {
    union { unsigned int i; float f; } v; v.i = ((unsigned int)h) << 16;
    return v.f;
}
static __device__ __forceinline__ void gload16(const void* g, void* l) {
    __builtin_amdgcn_global_load_lds(
        (const __attribute__((address_space(1))) unsigned int*)g,
        (__attribute__((address_space(3))) unsigned int*)l, 16, 0, 0);
}
// bijective XCD-chunked swizzle (m157/m204): blocks sharing panels land on one XCD.
static __device__ __forceinline__ int swz(int l, int n) {
    return (l & 7) * (n >> 3) + (l >> 3);
}

// ---- fused prep: tokens/latents f32->bf16 (4096 blk) + weight prep (512 blk) --
// No intra-launch dependencies: all blocks write disjoint regions from inputs.
__global__ __launch_bounds__(256) void cvt_prep(
    const float4* __restrict__ tok, const float4* __restrict__ lat,
    ushort4* __restrict__ tokd, ushort4* __restrict__ latd,
    const float* __restrict__ wl, const float* __restrict__ wt,
    const float4* __restrict__ wvl, const float4* __restrict__ wvt,
    const float* __restrict__ cw,
    ushort4* __restrict__ wlT, ushort4* __restrict__ wtT,
    ushort4* __restrict__ wvlb, ushort4* __restrict__ wvtb,
    unsigned int* __restrict__ wpb)
{
    const int bid = blockIdx.x;
    if (bid < 4096) {                           // bulk cvt: 6 independent loads/thread
        long t = bid * 256L + threadIdx.x;
        #pragma unroll
        for (int k = 0; k < 5; ++k) {
            long i = t + k * 1048576L;
            float4 f = tok[i];
            ushort4 u; u.x = f2bf(f.x); u.y = f2bf(f.y); u.z = f2bf(f.z); u.w = f2bf(f.w);
            tokd[i] = u;
        }
        float4 f = lat[t];
        ushort4 u; u.x = f2bf(f.x); u.y = f2bf(f.y); u.z = f2bf(f.z); u.w = f2bf(f.w);
        latd[t] = u;
        return;
    }
    // weight prep: grid-stride over 589,824 units with 512 blocks
    const long NW = 65536, NCV = 327680;
    for (long i = (bid - 4096) * 256L + threadIdx.x; i < 4 * NW + NCV;
         i += 512 * 256L) {
        long r = i;
        if (r < 2 * NW) {                       // transposed weight: wlT or wtT
            const float* src = (r < NW) ? wl : wt;
            ushort4* dst = (r < NW) ? wlT : wtT;
            long u = (r < NW) ? r : r - NW;
            int a = (int)(u >> 7), e4 = (int)(u & 127);
            ushort4 o;
            o.x = f2bf(src[(e4 * 4 + 0) * 512 + a]);
            o.y = f2bf(src[(e4 * 4 + 1) * 512 + a]);
            o.z = f2bf(src[(e4 * 4 + 2) * 512 + a]);
            o.w = f2bf(src[(e4 * 4 + 3) * 512 + a]);
            dst[a * 128 + e4] = o;
            continue;
        }
        r -= 2 * NW;
        const float4* s; ushort4* d;
        if (r < NW) { s = wvl; d = wvlb; }
        else if ((r -= NW) < NW) { s = wvt; d = wvtb; }
        else {
            r -= NW;  // conv unit: wp[e][k*128+c2] = {cw[e][2c2][k], cw[e][2c2+1][k]}
            long e = r / 640, rr = r % 640, k = rr >> 7, c2 = rr & 127;
            unsigned int lo = f2bf(cw[e * 1280 + (2 * c2) * 5 + k]);
            unsigned int hi = f2bf(cw[e * 1280 + (2 * c2 + 1) * 5 + k]);
            wpb[r] = lo | (hi << 16);
            continue;
        }
        float4 f = s[r];
        ushort4 u; u.x = f2bf(f.x); u.y = f2bf(f.y); u.z = f2bf(f.z); u.w = f2bf(f.w);
        d[r] = u;
    }
}

// ---------------- MFMA NT GEMM body: C[m,n] = sum_k A[m,k] * B[n,k] ----------
// 128x128 tile, BK=32, 4 waves (2x2 of 64x64), 16x16x32 bf16 MFMA.
// NBUF=3: triple-buffered 48KB, depth-2 prefetch (r9-proven).
// NBUF=2: double-buffered 32KB, depth-1 (r12-proven; full residency at 1024 blk).
// Scalar epilogue (r5-proven). All config compile-time/scalar (r6 lesson).
// AMODE: 0 = row m at A + m*lda.  1 = conv addressing into bf16 tokens.
// EPI:   0 = bf16 out (Cb) * scale
//        1 = +bias(f32, basep) then bf16 out (Cb)
//        2 = f32 base + acc -> C0,C1    3 = bf16 base + acc -> C0,C1
//        4 = EXP-score dual write: e=exp(v*scale); Cb normal (ldc) AND transposed
//            into (ushort*)C0 (ld bsC1); deterministic partial sums:
//            row-partials -> sumP0[z][m][32] (p=bx*2+wc),
//            col-partials -> sumP1[z][n][16] (p=by*2+wr).   (softmax fused out)
//        5 = f32 base + acc*inv -> C0,C1  (inv = 1/sum of 32 partials, rows 1024)
//        6 = bf16 base + acc*inv -> C0,C1 (inv = 1/sum of 16 partials, rows 2048)
template<int AMODE, int EPI, int NBUF, int NP = 0>
static __device__ __forceinline__ void mm_body(
    char* __restrict__ smc, int bx, int by, int z,
    const unsigned short* __restrict__ A, const unsigned short* __restrict__ B,
    long bsA, long bsB, int lda, int ldb, int K,
    unsigned short* __restrict__ Cb, long bsCb,
    float* __restrict__ C0, long bsC0, float* __restrict__ C1, long bsC1,
    const void* __restrict__ basep, long bsBase, int ldc, float scale,
    float* __restrict__ sumP0, float* __restrict__ sumP1)
{
    const int t = threadIdx.x, lane = t & 63, wid = t >> 6;
    const int m0 = by << 7, n0 = bx << 7;
    const unsigned short* Ab = A + (long)z * bsA;
    const unsigned short* Bb = B + (long)z * bsB;

    const int rA0 = wid * 16 + (lane >> 2);
    const int rA1 = rA0 + 64;
    const int cs0 = (lane & 3) ^ ((rA0 >> 1) & 3);
    const int cs1 = (lane & 3) ^ ((rA1 >> 1) & 3);

    long aoff0, aoff1;
    if (AMODE == 0) {
        aoff0 = (long)(m0 + rA0) * lda + cs0 * 8;
        aoff1 = (long)(m0 + rA1) * lda + cs1 * 8;
    } else {
        int ma = m0 + rA0, mb = m0 + rA1;
        aoff0 = (long)(ma >> 11) * 2621440 + (long)(ma & 2047) * 1280 + cs0 * 8;
        aoff1 = (long)(mb >> 11) * 2621440 + (long)(mb & 2047) * 1280 + cs1 * 8;
    }
    const long boff0 = (long)(n0 + rA0) * ldb + cs0 * 8;
    const long boff1 = (long)(n0 + rA1) * ldb + cs1 * 8;

    const int dA0 = (wid << 10), dA1 = ((wid + 4) << 10);
    const int dB0 = 8192 + (wid << 10), dB1 = 8192 + ((wid + 4) << 10);

    const int wr = wid >> 1, wc = wid & 1;
    const int l15 = lane & 15, cslot = lane >> 4;
    int offA[4], offB[4];
    #pragma unroll
    for (int i = 0; i < 4; ++i) {
        int r = wr * 64 + i * 16 + l15;
        offA[i] = r * 64 + ((cslot ^ ((r >> 1) & 3)) << 4);
        int rb = wc * 64 + i * 16 + l15;
        offB[i] = 8192 + rb * 64 + ((cslot ^ ((rb >> 1) & 3)) << 4);
    }

    f32x4 acc[4][4];
    #pragma unroll
    for (int i = 0; i < 4; ++i)
        #pragma unroll
        for (int j = 0; j < 4; ++j)
            acc[i][j] = (f32x4)(0.f);

#define STAGE(p, ktv) do {                                   \
        int kb_ = (ktv);                                     \
        int bo_ = (p) * 16384;                               \
        gload16(Ab + aoff0 + kb_, smc + bo_ + dA0);          \
        gload16(Ab + aoff1 + kb_, smc + bo_ + dA1);          \
        gload16(Bb + boff0 + kb_, smc + bo_ + dB0);          \
        gload16(Bb + boff1 + kb_, smc + bo_ + dB1);          \
    } while (0)
#define COMPUTE(c) do {                                                        \
        const char* base_ = smc + (c) * 16384;                                 \
        bf16x8 af[4], bfr[4];                                                  \
        _Pragma("unroll")                                                      \
        for (int i = 0; i < 4; ++i) af[i]  = *(const bf16x8*)(base_ + offA[i]);\
        _Pragma("unroll")                                                      \
        for (int i = 0; i < 4; ++i) bfr[i] = *(const bf16x8*)(base_ + offB[i]);\
        _Pragma("unroll")                                                      \
        for (int i = 0; i < 4; ++i)                                            \
            _Pragma("unroll")                                                  \
            for (int j = 0; j < 4; ++j)                                        \
                acc[i][j] = __builtin_amdgcn_mfma_f32_16x16x32_bf16(           \
                    af[i], bfr[j], acc[i][j], 0, 0, 0);                        \
    } while (0)

    const int nt = K >> 5;                      // always >= 2 here
    if constexpr (NBUF == 3) {
        STAGE(0, 0);
        STAGE(1, 32);
        int cur = 0;
        for (int it = 0; it < nt; ++it) {
            if (it + 2 < nt) {
                int nx2 = (cur >= 1) ? cur - 1 : 2;   // (cur+2)%3
                STAGE(nx2, (it + 2) << 5);
                asm volatile("s_waitcnt vmcnt(8)" ::: "memory");
            } else if (it + 1 < nt) {
                asm volatile("s_waitcnt vmcnt(4)" ::: "memory");
            } else {
                asm volatile("s_waitcnt vmcnt(0)" ::: "memory");
            }
            __builtin_amdgcn_s_barrier();
            COMPUTE(cur);
            asm volatile("s_waitcnt lgkmcnt(0)" ::: "memory");
            __builtin_amdgcn_s_barrier();
            cur = (cur + 1 == 3) ? 0 : cur + 1;
        }
    } else {
        STAGE(0, 0);
        int cur = 0;
        for (int it = 0; it < nt; ++it) {
            if (it + 1 < nt) {
                STAGE(cur ^ 1, (it + 1) << 5);
                asm volatile("s_waitcnt vmcnt(4)" ::: "memory");
            } else {
                asm volatile("s_waitcnt vmcnt(0)" ::: "memory");
            }
            __builtin_amdgcn_s_barrier();
            COMPUTE(cur);
            asm volatile("s_waitcnt lgkmcnt(0)" ::: "memory");
            __builtin_amdgcn_s_barrier();
            cur ^= 1;
        }
    }
#undef STAGE
#undef COMPUTE

    // epilogue: C/D frag layout col=lane&15, row=(lane>>4)*4+q  [m89-verified]
    const int colb = n0 + wc * 64 + l15;
    const int rowb = m0 + wr * 64 + cslot * 4;

    if (EPI == 4) {
        unsigned short* STp = (unsigned short*)C0;
        // exp(scale*v) in place
        #pragma unroll
        for (int i = 0; i < 4; ++i)
            #pragma unroll
            for (int j = 0; j < 4; ++j)
                #pragma unroll
                for (int q = 0; q < 4; ++q)
                    acc[i][j][q] = __expf(acc[i][j][q] * scale);
        // dual write (expS normal + transposed)
        #pragma unroll
        for (int i = 0; i < 4; ++i) {
            #pragma unroll
            for (int j = 0; j < 4; ++j) {
                int n = colb + j * 16;
                int mb = rowb + i * 16;
                unsigned short b0 = f2bf(acc[i][j][0]), b1 = f2bf(acc[i][j][1]);
                unsigned short b2 = f2bf(acc[i][j][2]), b3 = f2bf(acc[i][j][3]);
                unsigned short* sp = Cb + (long)z * bsCb + (long)mb * ldc + n;
                sp[0] = b0; sp[ldc] = b1; sp[2 * ldc] = b2; sp[3 * ldc] = b3;
                ushort4 st4; st4.x = b0; st4.y = b1; st4.z = b2; st4.w = b3;
                *(ushort4*)(STp + (long)z * bsC0 + (long)n * bsC1 + mb) = st4;
            }
        }
        // deterministic row partial sums (this wave's 64-col span)
        #pragma unroll
        for (int i = 0; i < 4; ++i) {
            #pragma unroll
            for (int q = 0; q < 4; ++q) {
                float rs = acc[i][0][q] + acc[i][1][q] + acc[i][2][q] + acc[i][3][q];
                #pragma unroll
                for (int msk = 1; msk < 16; msk <<= 1) rs += __shfl_xor(rs, msk);
                if (l15 == 0) {
                    int m = rowb + i * 16 + q;
                    sumP0[((long)z * 1024 + m) * 32 + bx * 2 + wc] = rs;
                }
            }
        }
        // deterministic col partial sums (this wave's 64-row span)
        #pragma unroll
        for (int j = 0; j < 4; ++j) {
            float cs = 0.f;
            #pragma unroll
            for (int i = 0; i < 4; ++i)
                #pragma unroll
                for (int q = 0; q < 4; ++q) cs += acc[i][j][q];
            cs += __shfl_xor(cs, 16);
            cs += __shfl_xor(cs, 32);
            if (cslot == 0) {
                int n = colb + j * 16;
                sumP1[((long)z * 2048 + n) * 16 + by * 2 + wr] = cs;
            }
        }
        return;
    }

    float* invt = nullptr;
    if (EPI == 5 || EPI == 6) {
        invt = (float*)smc;                     // LDS free after main loop
        if (t < 128) {
            const int rows = (EPI == 5) ? 1024 : 2048;
            const float* pp = sumP0 + ((long)z * rows + m0 + t) * NP;
            float s = 0.f;
            #pragma unroll
            for (int k = 0; k < NP; ++k) s += pp[k];
            invt[t] = 1.f / s;
        }
        __syncthreads();
    }

    #pragma unroll
    for (int i = 0; i < 4; ++i) {
        #pragma unroll
        for (int j = 0; j < 4; ++j) {
            int n = colb + j * 16;
            #pragma unroll
            for (int q = 0; q < 4; ++q) {
                int m = rowb + i * 16 + q;
                float v = acc[i][j][q];
                if (EPI == 0) {
                    Cb[(long)z * bsCb + (long)m * ldc + n] = f2bf(v * scale);
                } else if (EPI == 1) {
                    v += ((const float*)basep)[n];
                    Cb[(long)m * ldc + n] = f2bf(v);
                } else if (EPI == 2) {
                    float bv = ((const float*)basep)[(long)z * bsBase + (long)m * ldc + n];
                    float o = bv + v;
                    C0[(long)z * bsC0 + (long)m * ldc + n] = o;
                    C1[(long)z * bsC1 + (long)m * ldc + n] = o;
                } else if (EPI == 3) {
                    float bv = bf2f(((const unsigned short*)basep)[(long)z * bsBase + (long)m * ldc + n]);
                    float o = bv + v;
                    C0[(long)z * bsC0 + (long)m * ldc + n] = o;
                    C1[(long)z * bsC1 + (long)m * ldc + n] = o;
                } else if (EPI == 5) {
                    float vv = v * invt[(rowb - m0) + i * 16 + q];
                    float bv = ((const float*)basep)[(long)z * bsBase + (long)m * ldc + n];
                    float o = bv + vv;
                    C0[(long)z * bsC0 + (long)m * ldc + n] = o;
                    C1[(long)z * bsC1 + (long)m * ldc + n] = o;
                } else if (EPI == 6) {
                    float vv = v * invt[(rowb - m0) + i * 16 + q];
                    float bv = bf2f(((const unsigned short*)basep)[(long)z * bsBase + (long)m * ldc + n]);
                    float o = bv + vv;
                    C0[(long)z * bsC0 + (long)m * ldc + n] = o;
                    C1[(long)z * bsC1 + (long)m * ldc + n] = o;
                }
            }
        }
    }
}

// ---- grouped phase 1: conv (512) + V_latT (256) + Mt (16) = 784 blocks ----
// job-contiguous (r9-proven; r10/r11 interleaves broke L2 locality).
// Mt depends only on wlT/wtT from cvt_prep (previous launch).
__global__ __launch_bounds__(256) void gemm_g1(
    const unsigned short* __restrict__ tknb, const unsigned short* __restrict__ wpb,
    const float* __restrict__ conv_b, unsigned short* __restrict__ tokb,
    const unsigned short* __restrict__ latb,
    const unsigned short* __restrict__ wvlb, unsigned short* __restrict__ vlT,
    const unsigned short* __restrict__ wtT, const unsigned short* __restrict__ wlT,
    unsigned short* __restrict__ Mt)
{
    __shared__ unsigned short sm[24576];
    char* smc = (char*)sm;
    const int bid = blockIdx.x;
    if (bid < 512) {                            // conv: grid 4x128, K=1280 (longest first)
        int l = swz(bid, 512);
        mm_body<1, 1, 3>(smc, l & 3, l >> 2, 0, tknb, wpb, 0, 0, 1280, 1280, 1280,
                         tokb, 0, nullptr, 0, nullptr, 0, conv_b, 0, 512, 1.f,
                         nullptr, nullptr);
    } else if (bid < 768) {                     // V_latT: grid 8x4x8
        int l = swz(bid - 512, 256);
        mm_body<0, 0, 3>(smc, l & 7, (l >> 3) & 3, l >> 5, wvlb, latb, 0, 524288,
                         512, 512, 512, vlT, 524288, nullptr, 0, nullptr, 0,
                         nullptr, 0, 1024, 1.f, nullptr, nullptr);
    } else {                                    // Mt: grid 4x4, 16 blocks
        int l = bid - 768;
        mm_body<0, 0, 3>(smc, l & 3, l >> 2, 0, wtT, wlT, 0, 0, 512, 512, 512,
                         Mt, 0, nullptr, 0, nullptr, 0, nullptr, 0, 512, 1.f,
                         nullptr, nullptr);
    }
}

// ---- grouped phase 2: V_tokT (512) + P = lat*M (256) ----
__global__ __launch_bounds__(256) void gemm_g2(
    const unsigned short* __restrict__ tokb,
    const unsigned short* __restrict__ wvtb, unsigned short* __restrict__ vtT,
    const unsigned short* __restrict__ latb, const unsigned short* __restrict__ Mt,
    unsigned short* __restrict__ P)
{
    __shared__ unsigned short sm[24576];
    char* smc = (char*)sm;
    const int bid = blockIdx.x;
    if (bid < 512) {                            // V_tokT: grid 16x4x8
        int l = swz(bid, 512);
        mm_body<0, 0, 3>(smc, l & 15, (l >> 4) & 3, l >> 6, wvtb, tokb, 0, 1048576,
                         512, 512, 512, vtT, 1048576, nullptr, 0, nullptr, 0,
                         nullptr, 0, 2048, 1.f, nullptr, nullptr);
    } else {                                    // P: grid 4x64 (B = Mt, L2-resident)
        int l = swz(bid - 512, 256);
        mm_body<0, 0, 3>(smc, l & 3, l >> 2, 0, latb, Mt, 0, 0, 512, 512, 512,
                         P, 0, nullptr, 0, nullptr, 0, nullptr, 0, 512, 1.f,
                         nullptr, nullptr);
    }
}

// ---- score GEMM: expS = exp(scale * P tok^T), dual-written + partial sums ----
__global__ __launch_bounds__(256) void gemm_sc(
    const unsigned short* __restrict__ P, const unsigned short* __restrict__ tokb,
    unsigned short* __restrict__ S, unsigned short* __restrict__ ST,
    float* __restrict__ rsumP, float* __restrict__ csumP)
{
    __shared__ unsigned short sm[16384];
    int l = swz((int)blockIdx.x, 1024);         // grid 16x8x8: one z per XCD chunk
    mm_body<0, 4, 2>((char*)sm, l & 15, (l >> 4) & 7, l >> 7,
                     P, tokb, 524288, 1048576, 512, 512, 512,
                     S, 2097152, (float*)ST, 2097152, nullptr, 1024,
                     nullptr, 0, 2048, SCALEF, rsumP, csumP);
}

// ---- grouped phase 3: delta GEMMs with fused 1/rowsum + residual + dual write
__global__ __launch_bounds__(256) void gemm_g3(
    const unsigned short* __restrict__ S, const unsigned short* __restrict__ ST,
    const unsigned short* __restrict__ vlT, const unsigned short* __restrict__ vtT,
    const float* __restrict__ latents, const unsigned short* __restrict__ tokb,
    const float* __restrict__ rsumP, const float* __restrict__ csumP,
    float* __restrict__ out)
{
    __shared__ unsigned short sm[24576];
    char* smc = (char*)sm;
    const int bid = blockIdx.x;
    if (bid < 256) {                            // delta_lat: grid 4x8x8, K=2048
        int l = swz(bid, 256);
        mm_body<0, 5, 3, 32>(smc, l & 3, (l >> 2) & 7, l >> 5, S, vtT, 2097152, 1048576,
                             2048, 2048, 2048, nullptr, 0,
                             out, 524288, out + 12582912, 1572864,
                             latents, 524288, 512, 1.f, (float*)rsumP, nullptr);
    } else {                                    // delta_tok: grid 4x16x8, K=1024
        int l = swz(bid - 256, 512);
        mm_body<0, 6, 3, 16>(smc, l & 3, (l >> 2) & 15, l >> 6, ST, vlT, 2097152, 524288,
                             1024, 1024, 1024, nullptr, 0,
                             out + 4194304, 1048576, out + 12582912 + 524288, 1572864,
                             tokb, 1048576, 512, 1.f, (float*)csumP, nullptr);
    }
}

extern "C" void kernel_launch(void* const* d_in, const int* in_sizes, int n_in,
                              void* d_out, int out_size, void* d_ws, size_t ws_size,
                              hipStream_t stream)
{
    const float* latents = (const float*)d_in[0];
    const float* tokens  = (const float*)d_in[1];
    const float* W_lat   = (const float*)d_in[2];
    const float* W_tok   = (const float*)d_in[3];
    const float* W_vlat  = (const float*)d_in[4];
    const float* W_vtok  = (const float*)d_in[5];
    const float* conv_w  = (const float*)d_in[6];
    const float* conv_b  = (const float*)d_in[7];
    float* out = (float*)d_out;
    char* ws = (char*)d_ws;

    // workspace layout (bytes)
    unsigned short* S    = (unsigned short*)(ws);              // 8x1024x2048 bf16 = 33,554,432
    unsigned short* ST   = (unsigned short*)(ws + 33554432);   // 8x2048x1024 bf16
    unsigned short* tokb = (unsigned short*)(ws + 67108864);   // 8x2048x512  bf16 = 16,777,216
    unsigned short* latb = (unsigned short*)(ws + 83886080);   // 8x1024x512  bf16 =  8,388,608
    unsigned short* P    = (unsigned short*)(ws + 92274688);   // 8x1024x512  bf16 =  8,388,608
    unsigned short* Mt   = (unsigned short*)(ws + 100663296);  // 512x512     bf16 =    524,288
    float*          rsumP= (float*)(ws + 101187584);           // 8x1024x32 f32 = 1,048,576
    float*          csumP= (float*)(ws + 102236160);           // 8x2048x16 f32 = 1,048,576
    unsigned short* vlT  = (unsigned short*)(ws + 117440512);  // 8x512x1024 =  8,388,608
    unsigned short* vtT  = (unsigned short*)(ws + 125829120);  // 8x512x2048 = 16,777,216
    unsigned short* wpb  = (unsigned short*)(ws + 142606336);  // 512x1280   =  1,310,720
    unsigned short* wlT  = (unsigned short*)(ws + 143917056);  // 512x512 x4 =  2,097,152
    unsigned short* wtT  = (unsigned short*)(ws + 144441344);
    unsigned short* wvlb = (unsigned short*)(ws + 144965632);
    unsigned short* wvtb = (unsigned short*)(ws + 145489920);  // end 146,014,208
    // tokens-as-bf16 scratch lives in the concat region of d_out (overwritten by g3)
    unsigned short* tknb = (unsigned short*)(out + 12582912);  // 41,943,040 B <= 50,331,648 B

    // 1) fused conversions + weight prep (one launch, 4608 blocks)
    cvt_prep<<<4608, 256, 0, stream>>>(
        (const float4*)tokens, (const float4*)latents,
        (ushort4*)tknb, (ushort4*)latb,
        W_lat, W_tok, (const float4*)W_vlat, (const float4*)W_vtok, conv_w,
        (ushort4*)wlT, (ushort4*)wtT, (ushort4*)wvlb, (ushort4*)wvtb,
        (unsigned int*)wpb);

    // 2) conv-GEMM + V_latT + Mt (one launch, 784 blocks)
    gemm_g1<<<784, 256, 0, stream>>>(tknb, wpb, conv_b, tokb, latb, wvlb, vlT,
                                     wtT, wlT, Mt);

    // 3) V_tokT + P = lat*M (one launch, 768 blocks)
    gemm_g2<<<768, 256, 0, stream>>>(tokb, wvtb, vtT, latb, Mt, P);

    // 4) expS = exp(scale * P tok^T) dual-written + deterministic partial sums
    gemm_sc<<<1024, 256, 0, stream>>>(P, tokb, S, ST, rsumP, csumP);

    // 5) both delta GEMMs with fused 1/rowsum (one launch, 768 blocks)
    gemm_g3<<<768, 256, 0, stream>>>(S, ST, vlT, vtT, latents, tokb,
                                     rsumP, csumP, out);
}